// Round 1
// baseline (569.504 us; speedup 1.0000x reference)
//
#include <hip/hip_runtime.h>
#include <hip/hip_bf16.h>

#define NN 40000
#define NE 640000
#define DIM 128
#define OUTD 47

// ---------------- CSR build ----------------

__global__ void count_deg_kernel(const int* __restrict__ dst, int* __restrict__ deg, int n) {
    int i = blockIdx.x * blockDim.x + threadIdx.x;
    if (i < n) atomicAdd(&deg[dst[i]], 1);
}

__global__ __launch_bounds__(1024) void scan_kernel(const int* __restrict__ deg,
                                                    int* __restrict__ row_ptr, int n) {
    __shared__ int sums[1024];
    int tid = threadIdx.x;
    int chunk = (n + 1023) >> 10;
    int start = tid * chunk;
    int end = min(start + chunk, n);
    int s = 0;
    for (int i = start; i < end; ++i) s += deg[i];
    sums[tid] = s;
    __syncthreads();
    for (int off = 1; off < 1024; off <<= 1) {
        int v = (tid >= off) ? sums[tid - off] : 0;
        __syncthreads();
        sums[tid] += v;
        __syncthreads();
    }
    int run = (tid > 0) ? sums[tid - 1] : 0;
    for (int i = start; i < end; ++i) { row_ptr[i] = run; run += deg[i]; }
    if (tid == 0) row_ptr[n] = sums[1023];
}

__global__ void fill_csr_kernel(const int* __restrict__ src, const int* __restrict__ dst,
                                const int* __restrict__ row_ptr, int* __restrict__ cursor,
                                int* __restrict__ csr, int n) {
    int i = blockIdx.x * blockDim.x + threadIdx.x;
    if (i < n) {
        int d = dst[i];
        int pos = row_ptr[d] + atomicAdd(&cursor[d], 1);
        csr[pos] = src[i];
    }
}

// ---------------- neighbor mean: one wave per node ----------------

__global__ void aggregate_kernel(const float* __restrict__ h, const int* __restrict__ csr,
                                 const int* __restrict__ row_ptr, float* __restrict__ agg) {
    int node = (blockIdx.x * blockDim.x + threadIdx.x) >> 6;
    int lane = threadIdx.x & 63;
    if (node >= NN) return;
    int beg = row_ptr[node], end = row_ptr[node + 1];
    float a0 = 0.f, a1 = 0.f;
    for (int j = beg; j < end; ++j) {
        const float* hp = h + (size_t)csr[j] * DIM;
        a0 += hp[lane];
        a1 += hp[lane + 64];
    }
    float inv = 1.0f / fmaxf((float)(end - beg), 1.0f);
    agg[(size_t)node * DIM + lane] = a0 * inv;
    agg[(size_t)node * DIM + 64 + lane] = a1 * inv;
}

// ---------------- fused dual GEMM: out = h@Ws + agg@Wn + b (+relu) ----------------
// 64x64 tile per block, 256 threads, 4x4 acc per thread, combined K=256.

template <int NOUT, bool RELU>
__global__ __launch_bounds__(256) void sage_gemm_kernel(
    const float* __restrict__ hA, const float* __restrict__ agg,
    const float* __restrict__ Ws, const float* __restrict__ Wn,
    const float* __restrict__ bias, float* __restrict__ out) {
    __shared__ float W_lds[256 * 64];   // 64 KB: combined [Ws;Wn] panel, stride 64
    __shared__ float A_lds[32 * 68];    // A K-tile, transposed, stride 68 (2-way alias = free)

    int tid = threadIdx.x;
    int bm = blockIdx.x, bn = blockIdx.y;
    int ncol0 = bn * 64;

    // stage combined W panel
    if constexpr ((NOUT & 3) == 0) {
        for (int i = tid; i < 256 * 16; i += 256) {
            int k = i >> 4;
            int c4 = (i & 15) << 2;
            const float* wr = (k < DIM) ? (Ws + (size_t)k * NOUT) : (Wn + (size_t)(k - DIM) * NOUT);
            float4 v = *(const float4*)(wr + ncol0 + c4);
            *(float4*)&W_lds[(k << 6) + c4] = v;
        }
    } else {
        for (int i = tid; i < 256 * 64; i += 256) {
            int k = i >> 6;
            int c = i & 63;
            const float* wr = (k < DIM) ? (Ws + (size_t)k * NOUT) : (Wn + (size_t)(k - DIM) * NOUT);
            int col = ncol0 + c;
            W_lds[(k << 6) + c] = (col < NOUT) ? wr[col] : 0.0f;
        }
    }

    int r0 = (tid >> 4) << 2;   // 4 consecutive rows
    int c0 = (tid & 15) << 2;   // 4 consecutive cols
    int ar = tid >> 2;          // staging: row within tile
    int aq = tid & 3;           // staging: chunk pair
    size_t arow = (size_t)(bm * 64 + ar) * DIM;

    float acc[4][4] = {};

    for (int kt = 0; kt < 8; ++kt) {
        const float* base = (kt < 4) ? (hA + arow + kt * 32) : (agg + arow + (kt - 4) * 32);
        float4 v0 = *(const float4*)(base + (aq << 2));
        float4 v1 = *(const float4*)(base + (aq << 2) + 16);
        __syncthreads();  // previous iter's readers done
        int k0 = aq << 2;
        A_lds[(k0 + 0) * 68 + ar] = v0.x;
        A_lds[(k0 + 1) * 68 + ar] = v0.y;
        A_lds[(k0 + 2) * 68 + ar] = v0.z;
        A_lds[(k0 + 3) * 68 + ar] = v0.w;
        A_lds[(k0 + 16) * 68 + ar] = v1.x;
        A_lds[(k0 + 17) * 68 + ar] = v1.y;
        A_lds[(k0 + 18) * 68 + ar] = v1.z;
        A_lds[(k0 + 19) * 68 + ar] = v1.w;
        __syncthreads();
        int kw = kt << 5;
#pragma unroll
        for (int kk = 0; kk < 32; ++kk) {
            float4 a = *(const float4*)&A_lds[kk * 68 + r0];
            float4 w = *(const float4*)&W_lds[((kw + kk) << 6) + c0];
            float av[4] = {a.x, a.y, a.z, a.w};
            float wv[4] = {w.x, w.y, w.z, w.w};
#pragma unroll
            for (int i = 0; i < 4; ++i)
#pragma unroll
                for (int j = 0; j < 4; ++j) acc[i][j] += av[i] * wv[j];
        }
    }

#pragma unroll
    for (int i = 0; i < 4; ++i) {
        int row = bm * 64 + r0 + i;
        if constexpr ((NOUT & 3) == 0) {
            float4 o;
            o.x = acc[i][0] + bias[ncol0 + c0 + 0];
            o.y = acc[i][1] + bias[ncol0 + c0 + 1];
            o.z = acc[i][2] + bias[ncol0 + c0 + 2];
            o.w = acc[i][3] + bias[ncol0 + c0 + 3];
            if (RELU) {
                o.x = fmaxf(o.x, 0.f); o.y = fmaxf(o.y, 0.f);
                o.z = fmaxf(o.z, 0.f); o.w = fmaxf(o.w, 0.f);
            }
            *(float4*)&out[(size_t)row * NOUT + ncol0 + c0] = o;
        } else {
#pragma unroll
            for (int j = 0; j < 4; ++j) {
                int col = ncol0 + c0 + j;
                if (col < NOUT) {
                    float v = acc[i][j] + bias[col];
                    if (RELU) v = fmaxf(v, 0.f);
                    out[(size_t)row * NOUT + col] = v;
                }
            }
        }
    }
}

// ---------------- launch ----------------

extern "C" void kernel_launch(void* const* d_in, const int* in_sizes, int n_in,
                              void* d_out, int out_size, void* d_ws, size_t ws_size,
                              hipStream_t stream) {
    const float* x   = (const float*)d_in[0];
    const int*   src = (const int*)d_in[1];
    const int*   dst = (const int*)d_in[2];
    const float* Ws0 = (const float*)d_in[3];
    const float* Wn0 = (const float*)d_in[4];
    const float* b0  = (const float*)d_in[5];
    const float* Ws1 = (const float*)d_in[6];
    const float* Wn1 = (const float*)d_in[7];
    const float* b1  = (const float*)d_in[8];
    const float* Ws2 = (const float*)d_in[9];
    const float* Wn2 = (const float*)d_in[10];
    const float* b2  = (const float*)d_in[11];
    float* out = (float*)d_out;

    // workspace layout (int/float elements, 16B-aligned where vectorized)
    int* wsI     = (int*)d_ws;
    int* deg     = wsI;                 // 40000
    int* cursor  = wsI + 40000;         // 40000
    int* row_ptr = wsI + 80000;         // 40001
    int* csr     = wsI + 120004;        // 640000
    float* h1  = (float*)(wsI + 760004);            // 40000*128
    float* h2  = h1 + (size_t)NN * DIM;             // 40000*128
    float* agg = h2 + (size_t)NN * DIM;             // 40000*128

    hipMemsetAsync(deg, 0, 80000 * sizeof(int), stream);  // deg + cursor
    count_deg_kernel<<<(NE + 255) / 256, 256, 0, stream>>>(dst, deg, NE);
    scan_kernel<<<1, 1024, 0, stream>>>(deg, row_ptr, NN);
    fill_csr_kernel<<<(NE + 255) / 256, 256, 0, stream>>>(src, dst, row_ptr, cursor, csr, NE);

    dim3 g2(625, 2), g1(625, 1);

    aggregate_kernel<<<10000, 256, 0, stream>>>(x, csr, row_ptr, agg);
    sage_gemm_kernel<128, true><<<g2, 256, 0, stream>>>(x, agg, Ws0, Wn0, b0, h1);

    aggregate_kernel<<<10000, 256, 0, stream>>>(h1, csr, row_ptr, agg);
    sage_gemm_kernel<128, true><<<g2, 256, 0, stream>>>(h1, agg, Ws1, Wn1, b1, h2);

    aggregate_kernel<<<10000, 256, 0, stream>>>(h2, csr, row_ptr, agg);
    sage_gemm_kernel<47, false><<<g1, 256, 0, stream>>>(h2, agg, Ws2, Wn2, b2, out);
}

// Round 2
// 391.885 us; speedup vs baseline: 1.4532x; 1.4532x over previous
//
#include <hip/hip_runtime.h>
#include <hip/hip_bf16.h>

#define NN 40000
#define NE 640000

typedef __attribute__((ext_vector_type(8))) short bf16x8;
typedef __attribute__((ext_vector_type(4))) float f32x4;

static __device__ __forceinline__ unsigned short f2b(float f) {
    unsigned b = __float_as_uint(f);
    return (unsigned short)((b + 0x7FFFu + ((b >> 16) & 1u)) >> 16);
}
static __device__ __forceinline__ float b2f(unsigned short u) {
    return __uint_as_float(((unsigned)u) << 16);
}

// ---------------- CSR build ----------------

__global__ void count_deg_kernel(const int* __restrict__ dst, int* __restrict__ deg, int n) {
    int i = blockIdx.x * blockDim.x + threadIdx.x;
    if (i < n) atomicAdd(&deg[dst[i]], 1);
}

__global__ __launch_bounds__(1024) void scan_kernel(const int* __restrict__ deg,
                                                    int* __restrict__ row_ptr, int n) {
    __shared__ int sums[1024];
    int tid = threadIdx.x;
    int chunk = (n + 1023) >> 10;
    int start = tid * chunk;
    int end = min(start + chunk, n);
    int s = 0;
    for (int i = start; i < end; ++i) s += deg[i];
    sums[tid] = s;
    __syncthreads();
    for (int off = 1; off < 1024; off <<= 1) {
        int v = (tid >= off) ? sums[tid - off] : 0;
        __syncthreads();
        sums[tid] += v;
        __syncthreads();
    }
    int run = (tid > 0) ? sums[tid - 1] : 0;
    for (int i = start; i < end; ++i) { row_ptr[i] = run; run += deg[i]; }
    if (tid == 0) row_ptr[n] = sums[1023];
}

__global__ void fill_csr_kernel(const int* __restrict__ src, const int* __restrict__ dst,
                                const int* __restrict__ row_ptr, int* __restrict__ cursor,
                                int* __restrict__ csr, int n) {
    int i = blockIdx.x * blockDim.x + threadIdx.x;
    if (i < n) {
        int d = dst[i];
        int pos = row_ptr[d] + atomicAdd(&cursor[d], 1);
        csr[pos] = src[i];
    }
}

// ---------------- prep: cast x, transpose+cast weights ----------------

__global__ void cast_x_kernel(const float* __restrict__ x, unsigned short* __restrict__ Ab) {
    int i = blockIdx.x * blockDim.x + threadIdx.x;  // one per 4 elems
    if (i >= NN * 128 / 4) return;
    int e = i << 2;
    int node = e >> 7, c = e & 127;
    float4 v = *(const float4*)(x + e);
    uint2 o;
    o.x = f2b(v.x) | ((unsigned)f2b(v.y) << 16);
    o.y = f2b(v.z) | ((unsigned)f2b(v.w) << 16);
    *(uint2*)(Ab + (size_t)node * 256 + c) = o;
}

// Wt[n][k] (bf16, K=256 = [Wself; Wneigh]) from fp32 W[k][n]
__global__ void prep_w_kernel(const float* __restrict__ Ws0, const float* __restrict__ Wn0,
                              const float* __restrict__ Ws1, const float* __restrict__ Wn1,
                              const float* __restrict__ Ws2, const float* __restrict__ Wn2,
                              unsigned short* __restrict__ Wt0, unsigned short* __restrict__ Wt1,
                              unsigned short* __restrict__ Wt2) {
    int i = blockIdx.x * blockDim.x + threadIdx.x;
    if (i < 65536) {
        int l = i >> 15;
        int j = i & 32767;
        int n = j >> 8, k = j & 255;
        const float* Ws = l ? Ws1 : Ws0;
        const float* Wn = l ? Wn1 : Wn0;
        float v = (k < 128) ? Ws[k * 128 + n] : Wn[(k - 128) * 128 + n];
        (l ? Wt1 : Wt0)[n * 256 + k] = f2b(v);
    } else if (i < 65536 + 12288) {
        int j = i - 65536;
        int n = j >> 8, k = j & 255;  // n in [0,48), pad row 47..
        float v = 0.f;
        if (n < 47) v = (k < 128) ? Ws2[k * 47 + n] : Wn2[(k - 128) * 47 + n];
        Wt2[n * 256 + k] = f2b(v);
    }
}

// ---------------- neighbor mean (bf16 in/out, fp32 accum): one wave per node ----------------
// reads cols [0,128) of Ab, writes mean into cols [128,256)

__global__ void aggregate_kernel(unsigned short* __restrict__ Ab,
                                 const int* __restrict__ csr, const int* __restrict__ row_ptr) {
    int node = (blockIdx.x * blockDim.x + threadIdx.x) >> 6;
    int lane = threadIdx.x & 63;
    if (node >= NN) return;
    int beg = row_ptr[node], end = row_ptr[node + 1];
    float a0 = 0.f, a1 = 0.f;
    for (int j = beg; j < end; ++j) {
        unsigned v = *(const unsigned*)(Ab + (size_t)csr[j] * 256 + lane * 2);
        a0 += b2f((unsigned short)(v & 0xffff));
        a1 += b2f((unsigned short)(v >> 16));
    }
    float inv = 1.0f / fmaxf((float)(end - beg), 1.0f);
    unsigned w = f2b(a0 * inv) | ((unsigned)f2b(a1 * inv) << 16);
    *(unsigned*)(Ab + (size_t)node * 256 + 128 + lane * 2) = w;
}

// ---------------- MFMA GEMM: out = relu(A[M,256] @ Wt^T + b) ----------------
// B entirely in registers, A direct from global, no LDS, no barriers.
// Each wave owns NCPW 16-col tiles; 16 rows per M-tile; tpb M-tiles per block.

template <int NCPW, bool RELU, bool OUT_BF16>
__global__ __launch_bounds__(256) void gemm_kernel(
    const unsigned short* __restrict__ A, const unsigned short* __restrict__ Wt,
    const float* __restrict__ bias, void* __restrict__ outp, int tpb) {
    int wv = threadIdx.x >> 6, lane = threadIdx.x & 63;
    int lr = lane & 15, lg = lane >> 4;
    int ct0 = wv * NCPW;

    bf16x8 bfr[NCPW][8];
    float bs[NCPW];
#pragma unroll
    for (int c = 0; c < NCPW; ++c) {
        int n = (ct0 + c) * 16 + lr;
#pragma unroll
        for (int kt = 0; kt < 8; ++kt)
            bfr[c][kt] = *(const bf16x8*)(Wt + (size_t)n * 256 + kt * 32 + lg * 8);
        bs[c] = (n < (OUT_BF16 ? 128 : 47)) ? bias[n] : 0.f;
    }

    for (int tt = 0; tt < tpb; ++tt) {
        int m0 = (blockIdx.x * tpb + tt) * 16;
        bf16x8 afr[8];
#pragma unroll
        for (int kt = 0; kt < 8; ++kt)
            afr[kt] = *(const bf16x8*)(A + (size_t)(m0 + lr) * 256 + kt * 32 + lg * 8);
        f32x4 acc[NCPW];
#pragma unroll
        for (int c = 0; c < NCPW; ++c) acc[c] = (f32x4){0.f, 0.f, 0.f, 0.f};
#pragma unroll
        for (int kt = 0; kt < 8; ++kt)
#pragma unroll
            for (int c = 0; c < NCPW; ++c)
                acc[c] = __builtin_amdgcn_mfma_f32_16x16x32_bf16(afr[kt], bfr[c][kt], acc[c], 0, 0, 0);
#pragma unroll
        for (int c = 0; c < NCPW; ++c) {
            int n = (ct0 + c) * 16 + lr;
#pragma unroll
            for (int r = 0; r < 4; ++r) {
                int m = m0 + lg * 4 + r;
                float v = acc[c][r] + bs[c];
                if (RELU) v = fmaxf(v, 0.f);
                if (OUT_BF16) {
                    ((unsigned short*)outp)[(size_t)m * 256 + n] = f2b(v);
                } else {
                    if (n < 47) ((float*)outp)[(size_t)m * 47 + n] = v;
                }
            }
        }
    }
}

// ---------------- launch ----------------

extern "C" void kernel_launch(void* const* d_in, const int* in_sizes, int n_in,
                              void* d_out, int out_size, void* d_ws, size_t ws_size,
                              hipStream_t stream) {
    const float* x   = (const float*)d_in[0];
    const int*   src = (const int*)d_in[1];
    const int*   dst = (const int*)d_in[2];
    const float* Ws0 = (const float*)d_in[3];
    const float* Wn0 = (const float*)d_in[4];
    const float* b0  = (const float*)d_in[5];
    const float* Ws1 = (const float*)d_in[6];
    const float* Wn1 = (const float*)d_in[7];
    const float* b1  = (const float*)d_in[8];
    const float* Ws2 = (const float*)d_in[9];
    const float* Wn2 = (const float*)d_in[10];
    const float* b2  = (const float*)d_in[11];
    float* out = (float*)d_out;

    int* wsI     = (int*)d_ws;
    int* deg     = wsI;                 // 40000
    int* cursor  = wsI + 40000;         // 40000
    int* row_ptr = wsI + 80000;         // 40001
    int* csr     = wsI + 120004;        // 640000
    unsigned short* Ab0 = (unsigned short*)(wsI + 760004);  // [40000][256] bf16
    unsigned short* Ab1 = Ab0 + (size_t)NN * 256;
    unsigned short* Wt0 = Ab1 + (size_t)NN * 256;           // [128][256]
    unsigned short* Wt1 = Wt0 + 128 * 256;
    unsigned short* Wt2 = Wt1 + 128 * 256;                  // [48][256]
    // Ab2 aliases Ab0 (layer-0 activations dead by then)

    hipMemsetAsync(deg, 0, 80000 * sizeof(int), stream);
    count_deg_kernel<<<2500, 256, 0, stream>>>(dst, deg, NE);
    scan_kernel<<<1, 1024, 0, stream>>>(deg, row_ptr, NN);
    fill_csr_kernel<<<2500, 256, 0, stream>>>(src, dst, row_ptr, cursor, csr, NE);
    prep_w_kernel<<<304, 256, 0, stream>>>(Ws0, Wn0, Ws1, Wn1, Ws2, Wn2, Wt0, Wt1, Wt2);
    cast_x_kernel<<<5000, 256, 0, stream>>>(x, Ab0);

    aggregate_kernel<<<10000, 256, 0, stream>>>(Ab0, csr, row_ptr);
    gemm_kernel<2, true, true><<<1250, 256, 0, stream>>>(Ab0, Wt0, b0, Ab1, 2);

    aggregate_kernel<<<10000, 256, 0, stream>>>(Ab1, csr, row_ptr);
    gemm_kernel<2, true, true><<<1250, 256, 0, stream>>>(Ab1, Wt1, b1, Ab0, 2);

    aggregate_kernel<<<10000, 256, 0, stream>>>(Ab0, csr, row_ptr);
    gemm_kernel<1, false, false><<<1250, 192, 0, stream>>>(Ab0, Wt2, b2, out, 2);
}

// Round 3
// 294.088 us; speedup vs baseline: 1.9365x; 1.3325x over previous
//
#include <hip/hip_runtime.h>
#include <hip/hip_bf16.h>

#define NN 40000
#define NE 640000

typedef __attribute__((ext_vector_type(8))) short bf16x8;
typedef __attribute__((ext_vector_type(4))) float f32x4;

static __device__ __forceinline__ unsigned short f2b(float f) {
    unsigned b = __float_as_uint(f);
    return (unsigned short)((b + 0x7FFFu + ((b >> 16) & 1u)) >> 16);
}
static __device__ __forceinline__ float blo(unsigned v) { return __uint_as_float(v << 16); }
static __device__ __forceinline__ float bhi(unsigned v) { return __uint_as_float(v & 0xffff0000u); }

static __device__ __forceinline__ void acc8(float* a, uint4 v) {
    a[0] += blo(v.x); a[1] += bhi(v.x);
    a[2] += blo(v.y); a[3] += bhi(v.y);
    a[4] += blo(v.z); a[5] += bhi(v.z);
    a[6] += blo(v.w); a[7] += bhi(v.w);
}

// ---------------- CSR build ----------------

__global__ void count_deg_kernel(const int* __restrict__ dst, int* __restrict__ deg, int n) {
    int i = blockIdx.x * blockDim.x + threadIdx.x;
    if (i < n) atomicAdd(&deg[dst[i]], 1);
}

__global__ __launch_bounds__(1024) void scan_kernel(const int* __restrict__ deg,
                                                    int* __restrict__ row_ptr, int n) {
    __shared__ int sums[1024];
    int tid = threadIdx.x;
    int chunk = (n + 1023) >> 10;
    int start = tid * chunk;
    int end = min(start + chunk, n);
    int s = 0;
    for (int i = start; i < end; ++i) s += deg[i];
    sums[tid] = s;
    __syncthreads();
    for (int off = 1; off < 1024; off <<= 1) {
        int v = (tid >= off) ? sums[tid - off] : 0;
        __syncthreads();
        sums[tid] += v;
        __syncthreads();
    }
    int run = (tid > 0) ? sums[tid - 1] : 0;
    for (int i = start; i < end; ++i) { row_ptr[i] = run; run += deg[i]; }
    if (tid == 0) row_ptr[n] = sums[1023];
}

__global__ void fill_csr_kernel(const int* __restrict__ src, const int* __restrict__ dst,
                                const int* __restrict__ row_ptr, int* __restrict__ cursor,
                                int* __restrict__ csr, int n) {
    int i = blockIdx.x * blockDim.x + threadIdx.x;
    if (i < n) {
        int d = dst[i];
        int pos = row_ptr[d] + atomicAdd(&cursor[d], 1);
        csr[pos] = src[i];
    }
}

// ---------------- fused prep: zero deg/cursor + cast x + build Wt ----------------

__global__ __launch_bounds__(256) void prep_kernel(
    const float* __restrict__ x,
    const float* __restrict__ Ws0, const float* __restrict__ Wn0,
    const float* __restrict__ Ws1, const float* __restrict__ Wn1,
    const float* __restrict__ Ws2, const float* __restrict__ Wn2,
    int* __restrict__ zero_base, unsigned short* __restrict__ Ab0,
    unsigned short* __restrict__ Wt0, unsigned short* __restrict__ Wt1,
    unsigned short* __restrict__ Wt2s, unsigned short* __restrict__ Wt2n) {
    int b = blockIdx.x, tid = threadIdx.x;
    if (b < 79) {
        int i = (b * 256 + tid) * 4;
        if (i < 80000) *(int4*)(zero_base + i) = (int4){0, 0, 0, 0};
    } else if (b < 5079) {
        int i = (b - 79) * 256 + tid;   // one per 4 elems
        int e = i << 2;
        int node = e >> 7, c = e & 127;
        float4 v = *(const float4*)(x + e);
        uint2 o;
        o.x = f2b(v.x) | ((unsigned)f2b(v.y) << 16);
        o.y = f2b(v.z) | ((unsigned)f2b(v.w) << 16);
        *(uint2*)(Ab0 + (size_t)node * 256 + c) = o;
    } else {
        int i = (b - 5079) * 256 + tid;
        if (i < 65536) {
            int l = i >> 15, j = i & 32767;
            int n = j >> 8, k = j & 255;
            const float* Ws = l ? Ws1 : Ws0;
            const float* Wn = l ? Wn1 : Wn0;
            float v = (k < 128) ? Ws[k * 128 + n] : Wn[(k - 128) * 128 + n];
            (l ? Wt1 : Wt0)[n * 256 + k] = f2b(v);
        } else if (i < 65536 + 12288) {
            int j = i - 65536;
            int n = j >> 8, k = j & 255;        // self: K in [0,128), rows >=47 zero
            float v = (n < 47 && k < 128) ? Ws2[k * 47 + n] : 0.f;
            Wt2s[n * 256 + k] = f2b(v);
        } else {
            int j = i - 65536 - 12288;
            int n = j >> 8, k = j & 255;        // neigh: applied to h2 (cols [0,128))
            float v = (n < 47 && k < 128) ? Wn2[k * 47 + n] : 0.f;
            Wt2n[n * 256 + k] = f2b(v);
        }
    }
}

// ---------------- neighbor mean, 4 edge-groups x 16 lanes, unroll 2 ----------------
// reads cols [0,128) of Ab, writes mean into cols [128,256)

__global__ void aggregate_kernel(unsigned short* __restrict__ Ab,
                                 const int* __restrict__ csr,
                                 const int* __restrict__ row_ptr) {
    int node = (blockIdx.x * blockDim.x + threadIdx.x) >> 6;
    int lane = threadIdx.x & 63;
    if (node >= NN) return;
    int eg = lane >> 4, lc = lane & 15;
    int beg = row_ptr[node], end = row_ptr[node + 1];
    float a[8] = {};
    int j = beg + eg;
    for (; j + 4 < end; j += 8) {
        int s0 = csr[j], s1 = csr[j + 4];
        uint4 v0 = *(const uint4*)(Ab + (size_t)s0 * 256 + lc * 8);
        uint4 v1 = *(const uint4*)(Ab + (size_t)s1 * 256 + lc * 8);
        acc8(a, v0);
        acc8(a, v1);
    }
    if (j < end) {
        int s = csr[j];
        uint4 v = *(const uint4*)(Ab + (size_t)s * 256 + lc * 8);
        acc8(a, v);
    }
#pragma unroll
    for (int k = 0; k < 8; ++k) {
        a[k] += __shfl_xor(a[k], 16);
        a[k] += __shfl_xor(a[k], 32);
    }
    if (eg == 0) {
        float inv = 1.0f / fmaxf((float)(end - beg), 1.0f);
        uint4 o;
        o.x = f2b(a[0] * inv) | ((unsigned)f2b(a[1] * inv) << 16);
        o.y = f2b(a[2] * inv) | ((unsigned)f2b(a[3] * inv) << 16);
        o.z = f2b(a[4] * inv) | ((unsigned)f2b(a[5] * inv) << 16);
        o.w = f2b(a[6] * inv) | ((unsigned)f2b(a[7] * inv) << 16);
        *(uint4*)(Ab + (size_t)node * 256 + 128 + lc * 8) = o;
    }
}

// ---------------- layer-2 neighbor mean in 47-col space, += into out ----------------

__global__ void aggregate_out_kernel(const unsigned short* __restrict__ Hn,
                                     const int* __restrict__ csr,
                                     const int* __restrict__ row_ptr,
                                     float* __restrict__ out) {
    int node = (blockIdx.x * blockDim.x + threadIdx.x) >> 6;
    int lane = threadIdx.x & 63;
    if (node >= NN) return;
    int eg = lane >> 4, lc = lane & 15;
    int beg = row_ptr[node], end = row_ptr[node + 1];
    float a[4] = {};
    int j = beg + eg;
    for (; j + 4 < end; j += 8) {
        int s0 = csr[j], s1 = csr[j + 4];
        uint2 v0 = *(const uint2*)(Hn + (size_t)s0 * 64 + lc * 4);
        uint2 v1 = *(const uint2*)(Hn + (size_t)s1 * 64 + lc * 4);
        a[0] += blo(v0.x); a[1] += bhi(v0.x); a[2] += blo(v0.y); a[3] += bhi(v0.y);
        a[0] += blo(v1.x); a[1] += bhi(v1.x); a[2] += blo(v1.y); a[3] += bhi(v1.y);
    }
    if (j < end) {
        int s = csr[j];
        uint2 v = *(const uint2*)(Hn + (size_t)s * 64 + lc * 4);
        a[0] += blo(v.x); a[1] += bhi(v.x); a[2] += blo(v.y); a[3] += bhi(v.y);
    }
#pragma unroll
    for (int k = 0; k < 4; ++k) {
        a[k] += __shfl_xor(a[k], 16);
        a[k] += __shfl_xor(a[k], 32);
    }
    if (eg == 0) {
        float inv = 1.0f / fmaxf((float)(end - beg), 1.0f);
        int c0 = lc * 4;
#pragma unroll
        for (int r = 0; r < 4; ++r)
            if (c0 + r < 47) out[(size_t)node * 47 + c0 + r] += a[r] * inv;
    }
}

// ---------------- MFMA GEMM: B in registers, A direct from global ----------------

template <int NCPW, bool RELU, bool OUT_BF16, int OSTRIDE, bool HAS_BIAS>
__global__ __launch_bounds__(256) void gemm_kernel(
    const unsigned short* __restrict__ A, const unsigned short* __restrict__ Wt,
    const float* __restrict__ bias, void* __restrict__ outp, int tpb) {
    int wv = threadIdx.x >> 6, lane = threadIdx.x & 63;
    int lr = lane & 15, lg = lane >> 4;
    int ct0 = wv * NCPW;

    bf16x8 bfr[NCPW][8];
    float bs[NCPW];
#pragma unroll
    for (int c = 0; c < NCPW; ++c) {
        int n = (ct0 + c) * 16 + lr;
#pragma unroll
        for (int kt = 0; kt < 8; ++kt)
            bfr[c][kt] = *(const bf16x8*)(Wt + (size_t)n * 256 + kt * 32 + lg * 8);
        bs[c] = HAS_BIAS ? ((n < (OUT_BF16 ? 128 : 47)) ? bias[n] : 0.f) : 0.f;
    }

    for (int tt = 0; tt < tpb; ++tt) {
        int m0 = (blockIdx.x * tpb + tt) * 16;
        bf16x8 afr[8];
#pragma unroll
        for (int kt = 0; kt < 8; ++kt)
            afr[kt] = *(const bf16x8*)(A + (size_t)(m0 + lr) * 256 + kt * 32 + lg * 8);
        f32x4 acc[NCPW];
#pragma unroll
        for (int c = 0; c < NCPW; ++c) acc[c] = (f32x4){0.f, 0.f, 0.f, 0.f};
#pragma unroll
        for (int kt = 0; kt < 8; ++kt)
#pragma unroll
            for (int c = 0; c < NCPW; ++c)
                acc[c] = __builtin_amdgcn_mfma_f32_16x16x32_bf16(afr[kt], bfr[c][kt], acc[c], 0, 0, 0);
#pragma unroll
        for (int c = 0; c < NCPW; ++c) {
            int n = (ct0 + c) * 16 + lr;
#pragma unroll
            for (int r = 0; r < 4; ++r) {
                int m = m0 + lg * 4 + r;
                float v = acc[c][r] + bs[c];
                if (RELU) v = fmaxf(v, 0.f);
                if (OUT_BF16) {
                    ((unsigned short*)outp)[(size_t)m * OSTRIDE + n] = f2b(v);
                } else {
                    if (n < 47) ((float*)outp)[(size_t)m * 47 + n] = v;
                }
            }
        }
    }
}

// ---------------- launch ----------------

extern "C" void kernel_launch(void* const* d_in, const int* in_sizes, int n_in,
                              void* d_out, int out_size, void* d_ws, size_t ws_size,
                              hipStream_t stream) {
    const float* x   = (const float*)d_in[0];
    const int*   src = (const int*)d_in[1];
    const int*   dst = (const int*)d_in[2];
    const float* Ws0 = (const float*)d_in[3];
    const float* Wn0 = (const float*)d_in[4];
    const float* b0  = (const float*)d_in[5];
    const float* Ws1 = (const float*)d_in[6];
    const float* Wn1 = (const float*)d_in[7];
    const float* b1  = (const float*)d_in[8];
    const float* Ws2 = (const float*)d_in[9];
    const float* Wn2 = (const float*)d_in[10];
    const float* b2  = (const float*)d_in[11];
    float* out = (float*)d_out;

    int* wsI     = (int*)d_ws;
    int* deg     = wsI;                 // 40000
    int* cursor  = wsI + 40000;         // 40000
    int* row_ptr = wsI + 80000;         // 40001 (pad to 40004)
    int* csr     = wsI + 120004;        // 640000
    unsigned short* Ab0 = (unsigned short*)(wsI + 760004);  // [40000][256] bf16
    unsigned short* Ab1 = Ab0 + (size_t)NN * 256;           // [40000][256] bf16
    unsigned short* H2n = Ab1;                              // alias: Ab1 dead after gemm1
    unsigned short* Wt0 = Ab1 + (size_t)NN * 256;           // [128][256]
    unsigned short* Wt1 = Wt0 + 128 * 256;                  // [128][256]
    unsigned short* Wt2s = Wt1 + 128 * 256;                 // [48][256]
    unsigned short* Wt2n = Wt2s + 48 * 256;                 // [64][256]

    prep_kernel<<<5447, 256, 0, stream>>>(x, Ws0, Wn0, Ws1, Wn1, Ws2, Wn2,
                                          deg, Ab0, Wt0, Wt1, Wt2s, Wt2n);
    count_deg_kernel<<<2500, 256, 0, stream>>>(dst, deg, NE);
    scan_kernel<<<1, 1024, 0, stream>>>(deg, row_ptr, NN);
    fill_csr_kernel<<<2500, 256, 0, stream>>>(src, dst, row_ptr, cursor, csr, NE);

    // layer 0
    aggregate_kernel<<<10000, 256, 0, stream>>>(Ab0, csr, row_ptr);
    gemm_kernel<2, true, true, 256, true><<<1250, 256, 0, stream>>>(Ab0, Wt0, b0, Ab1, 2);
    // layer 1
    aggregate_kernel<<<10000, 256, 0, stream>>>(Ab1, csr, row_ptr);
    gemm_kernel<2, true, true, 256, true><<<1250, 256, 0, stream>>>(Ab1, Wt1, b1, Ab0, 2);
    // layer 2: out = h2@Ws2 + b2 + mean((h2@Wn2)[src])
    gemm_kernel<1, false, true, 64, false><<<1250, 256, 0, stream>>>(Ab0, Wt2n, nullptr, H2n, 2);
    gemm_kernel<1, false, false, 47, true><<<1250, 192, 0, stream>>>(Ab0, Wt2s, b2, out, 2);
    aggregate_out_kernel<<<10000, 256, 0, stream>>>(H2n, csr, row_ptr, out);
}

// Round 4
// 237.994 us; speedup vs baseline: 2.3929x; 1.2357x over previous
//
#include <hip/hip_runtime.h>
#include <hip/hip_bf16.h>

#define NN 40000
#define NE 640000
#define NB 157   // ceil(NN/256)

typedef __attribute__((ext_vector_type(8))) short bf16x8;
typedef __attribute__((ext_vector_type(4))) float f32x4;

static __device__ __forceinline__ unsigned short f2b(float f) {
    unsigned b = __float_as_uint(f);
    return (unsigned short)((b + 0x7FFFu + ((b >> 16) & 1u)) >> 16);
}
static __device__ __forceinline__ float blo(unsigned v) { return __uint_as_float(v << 16); }
static __device__ __forceinline__ float bhi(unsigned v) { return __uint_as_float(v & 0xffff0000u); }

static __device__ __forceinline__ void acc8(float* a, uint4 v) {
    a[0] += blo(v.x); a[1] += bhi(v.x);
    a[2] += blo(v.y); a[3] += bhi(v.y);
    a[4] += blo(v.z); a[5] += bhi(v.z);
    a[6] += blo(v.w); a[7] += bhi(v.w);
}
static __device__ __forceinline__ void acc4(float* a, uint2 v) {
    a[0] += blo(v.x); a[1] += bhi(v.x);
    a[2] += blo(v.y); a[3] += bhi(v.y);
}

// ---------------- CSR build ----------------

__global__ void count_deg_kernel(const int* __restrict__ dst, int* __restrict__ deg, int n) {
    int i = blockIdx.x * blockDim.x + threadIdx.x;
    if (i < n) atomicAdd(&deg[dst[i]], 1);
}

// level 1: per-block (256-elem) sums
__global__ __launch_bounds__(256) void scan1_kernel(const int* __restrict__ deg,
                                                    int* __restrict__ bsum) {
    int i = blockIdx.x * 256 + threadIdx.x;
    int v = (i < NN) ? deg[i] : 0;
#pragma unroll
    for (int off = 1; off < 64; off <<= 1) v += __shfl_xor(v, off);
    __shared__ int ws4[4];
    if ((threadIdx.x & 63) == 0) ws4[threadIdx.x >> 6] = v;
    __syncthreads();
    if (threadIdx.x == 0) bsum[blockIdx.x] = ws4[0] + ws4[1] + ws4[2] + ws4[3];
}

// level 2: exclusive scan of NB block sums (one wave)
__global__ void scan_top_kernel(const int* __restrict__ bsum, int* __restrict__ btop) {
    int lane = threadIdx.x;
    int run = 0;
    for (int base = 0; base < NB; base += 64) {
        int idx = base + lane;
        int v = (idx < NB) ? bsum[idx] : 0;
        int s = v;
#pragma unroll
        for (int off = 1; off < 64; off <<= 1) { int t = __shfl_up(s, off); if (lane >= off) s += t; }
        if (idx < NB) btop[idx] = run + s - v;
        run += __shfl(s, 63);
    }
}

// level 3: per-block exclusive scan + block offset -> row_ptr
__global__ __launch_bounds__(256) void scan2_kernel(const int* __restrict__ deg,
                                                    const int* __restrict__ btop,
                                                    int* __restrict__ row_ptr) {
    int b = blockIdx.x;
    int i = b * 256 + threadIdx.x;
    int lane = threadIdx.x & 63, wv = threadIdx.x >> 6;
    int v = (i < NN) ? deg[i] : 0;
    int s = v;
#pragma unroll
    for (int off = 1; off < 64; off <<= 1) { int t = __shfl_up(s, off); if (lane >= off) s += t; }
    __shared__ int wsum[4];
    if (lane == 63) wsum[wv] = s;
    __syncthreads();
    int add = btop[b];
    for (int w = 0; w < wv; ++w) add += wsum[w];
    if (i < NN) row_ptr[i] = add + s - v;
    if (i == NN - 1) row_ptr[NN] = add + s;
}

__global__ void fill_csr_kernel(const int* __restrict__ src, const int* __restrict__ dst,
                                const int* __restrict__ row_ptr, int* __restrict__ cursor,
                                int* __restrict__ csr, int n) {
    int i = blockIdx.x * blockDim.x + threadIdx.x;
    if (i < n) {
        int d = dst[i];
        int pos = row_ptr[d] + atomicAdd(&cursor[d], 1);
        csr[pos] = src[i];
    }
}

// ---------------- fused prep: zero deg/cursor + cast x + build Wt ----------------

__global__ __launch_bounds__(256) void prep_kernel(
    const float* __restrict__ x,
    const float* __restrict__ Ws0, const float* __restrict__ Wn0,
    const float* __restrict__ Ws1, const float* __restrict__ Wn1,
    const float* __restrict__ Ws2, const float* __restrict__ Wn2,
    int* __restrict__ zero_base, unsigned short* __restrict__ Ab0,
    unsigned short* __restrict__ Wt0, unsigned short* __restrict__ Wt1,
    unsigned short* __restrict__ Wt2s, unsigned short* __restrict__ Wt2n) {
    int b = blockIdx.x, tid = threadIdx.x;
    if (b < 79) {
        int i = (b * 256 + tid) * 4;
        if (i < 80000) *(int4*)(zero_base + i) = (int4){0, 0, 0, 0};
    } else if (b < 5079) {
        int i = (b - 79) * 256 + tid;   // one per 4 elems
        int e = i << 2;
        int node = e >> 7, c = e & 127;
        float4 v = *(const float4*)(x + e);
        uint2 o;
        o.x = f2b(v.x) | ((unsigned)f2b(v.y) << 16);
        o.y = f2b(v.z) | ((unsigned)f2b(v.w) << 16);
        *(uint2*)(Ab0 + (size_t)node * 256 + c) = o;
    } else {
        int i = (b - 5079) * 256 + tid;
        if (i < 65536) {
            int l = i >> 15, j = i & 32767;
            int n = j >> 8, k = j & 255;
            const float* Ws = l ? Ws1 : Ws0;
            const float* Wn = l ? Wn1 : Wn0;
            float v = (k < 128) ? Ws[k * 128 + n] : Wn[(k - 128) * 128 + n];
            (l ? Wt1 : Wt0)[n * 256 + k] = f2b(v);
        } else if (i < 65536 + 12288) {
            int j = i - 65536;
            int n = j >> 8, k = j & 255;        // self: K in [0,128), rows >=47 zero
            float v = (n < 47 && k < 128) ? Ws2[k * 47 + n] : 0.f;
            Wt2s[n * 256 + k] = f2b(v);
        } else {
            int j = i - 65536 - 12288;          // 16384 elems -> 64 rows
            int n = j >> 8, k = j & 255;        // neigh: applied to h2 (cols [0,128))
            float v = (n < 47 && k < 128) ? Wn2[k * 47 + n] : 0.f;
            Wt2n[n * 256 + k] = f2b(v);
        }
    }
}

// ---------------- neighbor mean, 4 edge-groups x 16 lanes, unroll 4 ----------------
// reads cols [0,128) of Ab, writes mean into cols [128,256)

__global__ void aggregate_kernel(unsigned short* __restrict__ Ab,
                                 const int* __restrict__ csr,
                                 const int* __restrict__ row_ptr) {
    int node = (blockIdx.x * blockDim.x + threadIdx.x) >> 6;
    int lane = threadIdx.x & 63;
    if (node >= NN) return;
    int eg = lane >> 4, lc = lane & 15;
    int beg = row_ptr[node], end = row_ptr[node + 1];
    float a[8] = {};
    int j = beg + eg;
    for (; j + 12 < end; j += 16) {
        int s0 = csr[j], s1 = csr[j + 4], s2 = csr[j + 8], s3 = csr[j + 12];
        uint4 v0 = *(const uint4*)(Ab + (size_t)s0 * 256 + lc * 8);
        uint4 v1 = *(const uint4*)(Ab + (size_t)s1 * 256 + lc * 8);
        uint4 v2 = *(const uint4*)(Ab + (size_t)s2 * 256 + lc * 8);
        uint4 v3 = *(const uint4*)(Ab + (size_t)s3 * 256 + lc * 8);
        acc8(a, v0); acc8(a, v1); acc8(a, v2); acc8(a, v3);
    }
    for (; j < end; j += 4) {
        int s = csr[j];
        uint4 v = *(const uint4*)(Ab + (size_t)s * 256 + lc * 8);
        acc8(a, v);
    }
#pragma unroll
    for (int k = 0; k < 8; ++k) {
        a[k] += __shfl_xor(a[k], 16);
        a[k] += __shfl_xor(a[k], 32);
    }
    if (eg == 0) {
        float inv = 1.0f / fmaxf((float)(end - beg), 1.0f);
        uint4 o;
        o.x = f2b(a[0] * inv) | ((unsigned)f2b(a[1] * inv) << 16);
        o.y = f2b(a[2] * inv) | ((unsigned)f2b(a[3] * inv) << 16);
        o.z = f2b(a[4] * inv) | ((unsigned)f2b(a[5] * inv) << 16);
        o.w = f2b(a[6] * inv) | ((unsigned)f2b(a[7] * inv) << 16);
        *(uint4*)(Ab + (size_t)node * 256 + 128 + lc * 8) = o;
    }
}

// ---------------- layer-2 neighbor mean in 47-col space, += into out ----------------

__global__ void aggregate_out_kernel(const unsigned short* __restrict__ Hn,
                                     const int* __restrict__ csr,
                                     const int* __restrict__ row_ptr,
                                     float* __restrict__ out) {
    int node = (blockIdx.x * blockDim.x + threadIdx.x) >> 6;
    int lane = threadIdx.x & 63;
    if (node >= NN) return;
    int eg = lane >> 4, lc = lane & 15;
    int beg = row_ptr[node], end = row_ptr[node + 1];
    float a[4] = {};
    int j = beg + eg;
    for (; j + 12 < end; j += 16) {
        int s0 = csr[j], s1 = csr[j + 4], s2 = csr[j + 8], s3 = csr[j + 12];
        uint2 v0 = *(const uint2*)(Hn + (size_t)s0 * 64 + lc * 4);
        uint2 v1 = *(const uint2*)(Hn + (size_t)s1 * 64 + lc * 4);
        uint2 v2 = *(const uint2*)(Hn + (size_t)s2 * 64 + lc * 4);
        uint2 v3 = *(const uint2*)(Hn + (size_t)s3 * 64 + lc * 4);
        acc4(a, v0); acc4(a, v1); acc4(a, v2); acc4(a, v3);
    }
    for (; j < end; j += 4) {
        int s = csr[j];
        uint2 v = *(const uint2*)(Hn + (size_t)s * 64 + lc * 4);
        acc4(a, v);
    }
#pragma unroll
    for (int k = 0; k < 4; ++k) {
        a[k] += __shfl_xor(a[k], 16);
        a[k] += __shfl_xor(a[k], 32);
    }
    if (eg == 0) {
        float inv = 1.0f / fmaxf((float)(end - beg), 1.0f);
        int c0 = lc * 4;
#pragma unroll
        for (int r = 0; r < 4; ++r)
            if (c0 + r < 47) out[(size_t)node * 47 + c0 + r] += a[r] * inv;
    }
}

// ---------------- MFMA GEMM: B in registers, A direct from global ----------------

template <int NCPW, bool RELU, bool OUT_BF16, int OSTRIDE, bool HAS_BIAS>
__global__ __launch_bounds__(256) void gemm_kernel(
    const unsigned short* __restrict__ A, const unsigned short* __restrict__ Wt,
    const float* __restrict__ bias, void* __restrict__ outp, int tpb) {
    int wv = threadIdx.x >> 6, lane = threadIdx.x & 63;
    int lr = lane & 15, lg = lane >> 4;
    int ct0 = wv * NCPW;

    bf16x8 bfr[NCPW][8];
    float bs[NCPW];
#pragma unroll
    for (int c = 0; c < NCPW; ++c) {
        int n = (ct0 + c) * 16 + lr;
#pragma unroll
        for (int kt = 0; kt < 8; ++kt)
            bfr[c][kt] = *(const bf16x8*)(Wt + (size_t)n * 256 + kt * 32 + lg * 8);
        bs[c] = HAS_BIAS ? ((n < (OUT_BF16 ? 128 : 47)) ? bias[n] : 0.f) : 0.f;
    }

    for (int tt = 0; tt < tpb; ++tt) {
        int m0 = (blockIdx.x * tpb + tt) * 16;
        bf16x8 afr[8];
#pragma unroll
        for (int kt = 0; kt < 8; ++kt)
            afr[kt] = *(const bf16x8*)(A + (size_t)(m0 + lr) * 256 + kt * 32 + lg * 8);
        f32x4 acc[NCPW];
#pragma unroll
        for (int c = 0; c < NCPW; ++c) acc[c] = (f32x4){0.f, 0.f, 0.f, 0.f};
#pragma unroll
        for (int kt = 0; kt < 8; ++kt)
#pragma unroll
            for (int c = 0; c < NCPW; ++c)
                acc[c] = __builtin_amdgcn_mfma_f32_16x16x32_bf16(afr[kt], bfr[c][kt], acc[c], 0, 0, 0);
#pragma unroll
        for (int c = 0; c < NCPW; ++c) {
            int n = (ct0 + c) * 16 + lr;
#pragma unroll
            for (int r = 0; r < 4; ++r) {
                int m = m0 + lg * 4 + r;
                float v = acc[c][r] + bs[c];
                if (RELU) v = fmaxf(v, 0.f);
                if (OUT_BF16) {
                    ((unsigned short*)outp)[(size_t)m * OSTRIDE + n] = f2b(v);
                } else {
                    if (n < 47) ((float*)outp)[(size_t)m * 47 + n] = v;
                }
            }
        }
    }
}

// ---------------- launch ----------------

extern "C" void kernel_launch(void* const* d_in, const int* in_sizes, int n_in,
                              void* d_out, int out_size, void* d_ws, size_t ws_size,
                              hipStream_t stream) {
    const float* x   = (const float*)d_in[0];
    const int*   src = (const int*)d_in[1];
    const int*   dst = (const int*)d_in[2];
    const float* Ws0 = (const float*)d_in[3];
    const float* Wn0 = (const float*)d_in[4];
    const float* b0  = (const float*)d_in[5];
    const float* Ws1 = (const float*)d_in[6];
    const float* Wn1 = (const float*)d_in[7];
    const float* b1  = (const float*)d_in[8];
    const float* Ws2 = (const float*)d_in[9];
    const float* Wn2 = (const float*)d_in[10];
    const float* b2  = (const float*)d_in[11];
    float* out = (float*)d_out;

    int* wsI     = (int*)d_ws;
    int* deg     = wsI;                 // 40000
    int* cursor  = wsI + 40000;         // 40000
    int* row_ptr = wsI + 80000;         // 40001 (pad to 40004)
    int* csr     = wsI + 120004;        // 640000
    unsigned short* Ab0 = (unsigned short*)(wsI + 760004);  // [40000][256] bf16
    unsigned short* Ab1 = Ab0 + (size_t)NN * 256;           // [40000][256] bf16
    unsigned short* H2n = Ab1;                              // alias: Ab1 dead after gemm1
    unsigned short* Wt0 = Ab1 + (size_t)NN * 256;           // [128][256]
    unsigned short* Wt1 = Wt0 + 128 * 256;                  // [128][256]
    unsigned short* Wt2s = Wt1 + 128 * 256;                 // [48][256]
    unsigned short* Wt2n = Wt2s + 48 * 256;                 // [64][256]
    int* bsum = (int*)(Wt2n + 64 * 256);                    // [NB]
    int* btop = bsum + NB;                                  // [NB]

    prep_kernel<<<5447, 256, 0, stream>>>(x, Ws0, Wn0, Ws1, Wn1, Ws2, Wn2,
                                          deg, Ab0, Wt0, Wt1, Wt2s, Wt2n);
    count_deg_kernel<<<2500, 256, 0, stream>>>(dst, deg, NE);
    scan1_kernel<<<NB, 256, 0, stream>>>(deg, bsum);
    scan_top_kernel<<<1, 64, 0, stream>>>(bsum, btop);
    scan2_kernel<<<NB, 256, 0, stream>>>(deg, btop, row_ptr);
    fill_csr_kernel<<<2500, 256, 0, stream>>>(src, dst, row_ptr, cursor, csr, NE);

    // layer 0
    aggregate_kernel<<<10000, 256, 0, stream>>>(Ab0, csr, row_ptr);
    gemm_kernel<2, true, true, 256, true><<<1250, 256, 0, stream>>>(Ab0, Wt0, b0, Ab1, 2);
    // layer 1
    aggregate_kernel<<<10000, 256, 0, stream>>>(Ab1, csr, row_ptr);
    gemm_kernel<2, true, true, 256, true><<<1250, 256, 0, stream>>>(Ab1, Wt1, b1, Ab0, 2);
    // layer 2: out = h2@Ws2 + b2 + mean((h2@Wn2)[src])
    gemm_kernel<1, false, true, 64, false><<<1250, 256, 0, stream>>>(Ab0, Wt2n, nullptr, H2n, 2);
    gemm_kernel<1, false, false, 47, true><<<1250, 192, 0, stream>>>(Ab0, Wt2s, b2, out, 2);
    aggregate_out_kernel<<<10000, 256, 0, stream>>>(H2n, csr, row_ptr, out);
}

// Round 5
// 216.438 us; speedup vs baseline: 2.6313x; 1.0996x over previous
//
#include <hip/hip_runtime.h>
#include <hip/hip_bf16.h>

#define NN 40000
#define NE 640000
#define NB 157   // ceil(NN/256)

typedef __attribute__((ext_vector_type(8))) short bf16x8;
typedef __attribute__((ext_vector_type(4))) float f32x4;

static __device__ __forceinline__ unsigned short f2b(float f) {
    unsigned b = __float_as_uint(f);
    return (unsigned short)((b + 0x7FFFu + ((b >> 16) & 1u)) >> 16);
}
static __device__ __forceinline__ float blo(unsigned v) { return __uint_as_float(v << 16); }
static __device__ __forceinline__ float bhi(unsigned v) { return __uint_as_float(v & 0xffff0000u); }

static __device__ __forceinline__ void acc8(float* a, uint4 v) {
    a[0] += blo(v.x); a[1] += bhi(v.x);
    a[2] += blo(v.y); a[3] += bhi(v.y);
    a[4] += blo(v.z); a[5] += bhi(v.z);
    a[6] += blo(v.w); a[7] += bhi(v.w);
}
static __device__ __forceinline__ void acc4(float* a, uint2 v) {
    a[0] += blo(v.x); a[1] += bhi(v.x);
    a[2] += blo(v.y); a[3] += bhi(v.y);
}

// ---------------- CSR build ----------------

__global__ void count_deg_kernel(const int* __restrict__ dst, int* __restrict__ deg, int n) {
    int i = blockIdx.x * blockDim.x + threadIdx.x;
    if (i < n) atomicAdd(&deg[dst[i]], 1);
}

__global__ __launch_bounds__(256) void scan1_kernel(const int* __restrict__ deg,
                                                    int* __restrict__ bsum) {
    int i = blockIdx.x * 256 + threadIdx.x;
    int v = (i < NN) ? deg[i] : 0;
#pragma unroll
    for (int off = 1; off < 64; off <<= 1) v += __shfl_xor(v, off);
    __shared__ int ws4[4];
    if ((threadIdx.x & 63) == 0) ws4[threadIdx.x >> 6] = v;
    __syncthreads();
    if (threadIdx.x == 0) bsum[blockIdx.x] = ws4[0] + ws4[1] + ws4[2] + ws4[3];
}

__global__ void scan_top_kernel(const int* __restrict__ bsum, int* __restrict__ btop) {
    int lane = threadIdx.x;
    int run = 0;
    for (int base = 0; base < NB; base += 64) {
        int idx = base + lane;
        int v = (idx < NB) ? bsum[idx] : 0;
        int s = v;
#pragma unroll
        for (int off = 1; off < 64; off <<= 1) { int t = __shfl_up(s, off); if (lane >= off) s += t; }
        if (idx < NB) btop[idx] = run + s - v;
        run += __shfl(s, 63);
    }
}

__global__ __launch_bounds__(256) void scan2_kernel(const int* __restrict__ deg,
                                                    const int* __restrict__ btop,
                                                    int* __restrict__ row_ptr) {
    int b = blockIdx.x;
    int i = b * 256 + threadIdx.x;
    int lane = threadIdx.x & 63, wv = threadIdx.x >> 6;
    int v = (i < NN) ? deg[i] : 0;
    int s = v;
#pragma unroll
    for (int off = 1; off < 64; off <<= 1) { int t = __shfl_up(s, off); if (lane >= off) s += t; }
    __shared__ int wsum[4];
    if (lane == 63) wsum[wv] = s;
    __syncthreads();
    int add = btop[b];
    for (int w = 0; w < wv; ++w) add += wsum[w];
    if (i < NN) row_ptr[i] = add + s - v;
    if (i == NN - 1) row_ptr[NN] = add + s;
}

__global__ void fill_csr_kernel(const int* __restrict__ src, const int* __restrict__ dst,
                                const int* __restrict__ row_ptr, int* __restrict__ cursor,
                                int* __restrict__ csr, int n) {
    int i = blockIdx.x * blockDim.x + threadIdx.x;
    if (i < n) {
        int d = dst[i];
        int pos = row_ptr[d] + atomicAdd(&cursor[d], 1);
        csr[pos] = src[i];
    }
}

// ---------------- fused prep: zero deg/cursor + cast x + build weights ----------------

__global__ __launch_bounds__(256) void prep_kernel(
    const float* __restrict__ x,
    const float* __restrict__ Ws0, const float* __restrict__ Wn0,
    const float* __restrict__ Ws1, const float* __restrict__ Wn1,
    const float* __restrict__ Ws2, const float* __restrict__ Wn2,
    int* __restrict__ zero_base, unsigned short* __restrict__ X,
    unsigned short* __restrict__ Wt0, unsigned short* __restrict__ Wt1,
    unsigned short* __restrict__ Wt2s, unsigned short* __restrict__ Wt2n) {
    int b = blockIdx.x, tid = threadIdx.x;
    if (b < 79) {
        int i = (b * 256 + tid) * 4;
        if (i < 80000) *(int4*)(zero_base + i) = (int4){0, 0, 0, 0};
    } else if (b < 5079) {
        int i = (b - 79) * 256 + tid;   // one per 4 elems of x
        int e = i << 2;
        float4 v = *(const float4*)(x + e);
        uint2 o;
        o.x = f2b(v.x) | ((unsigned)f2b(v.y) << 16);
        o.y = f2b(v.z) | ((unsigned)f2b(v.w) << 16);
        *(uint2*)(X + e) = o;   // X is [NN][128], same flat layout as x
    } else {
        int i = (b - 5079) * 256 + tid;
        if (i < 65536) {
            // Wt0/Wt1: [128 n][256 k], k<128 = Ws rows, k>=128 = Wn rows
            int l = i >> 15, j = i & 32767;
            int n = j >> 8, k = j & 255;
            const float* Ws = l ? Ws1 : Ws0;
            const float* Wn = l ? Wn1 : Wn0;
            float v = (k < 128) ? Ws[k * 128 + n] : Wn[(k - 128) * 128 + n];
            (l ? Wt1 : Wt0)[n * 256 + k] = f2b(v);
        } else if (i < 65536 + 6144) {
            int j = i - 65536;                  // Wt2s: [48 n][128 k]
            int n = j >> 7, k = j & 127;
            float v = (n < 47) ? Ws2[k * 47 + n] : 0.f;
            Wt2s[n * 128 + k] = f2b(v);
        } else if (i < 65536 + 12288) {
            int j = i - 65536 - 6144;           // Wt2n: [48 n][128 k]
            int n = j >> 7, k = j & 127;
            float v = (n < 47) ? Wn2[k * 47 + n] : 0.f;
            Wt2n[n * 128 + k] = f2b(v);
        }
    }
}

// ---------------- fused SAGE layer: gather-mean into LDS, then dual-path MFMA ----------------
// Hin/Hout: [NN][128] bf16. Wt: [128 n][256 k] (k<128 self, k>=128 neigh).
// Block = 256 threads / 4 waves, 64 nodes. Each wave gathers 16 nodes then owns 2 col-tiles.

template <bool RELU>
__global__ __launch_bounds__(256) void sage_layer_kernel(
    const unsigned short* __restrict__ Hin,
    const int* __restrict__ csr, const int* __restrict__ row_ptr,
    const unsigned short* __restrict__ Wt, const float* __restrict__ bias,
    unsigned short* __restrict__ Hout) {
    // [64 rows][16 chunks of 16B], chunk XOR-swizzled by (row&15) to kill bank conflicts
    __shared__ unsigned short agg_lds[64 * 128];

    int tid = threadIdx.x;
    int wv = tid >> 6, lane = tid & 63;
    int lr = lane & 15, lg = lane >> 4;
    int m0 = blockIdx.x * 64;

    // preload B fragments (2 col-tiles per wave) + bias
    bf16x8 bfr[2][8];
    float bs[2];
#pragma unroll
    for (int c = 0; c < 2; ++c) {
        int n = (wv * 2 + c) * 16 + lr;
#pragma unroll
        for (int kt = 0; kt < 8; ++kt)
            bfr[c][kt] = *(const bf16x8*)(Wt + (size_t)n * 256 + kt * 32 + lg * 8);
        bs[c] = bias[n];
    }

    // phase 1: gather-mean for this wave's 16 nodes (4 edge-groups x 16 lanes)
    int nb = m0 + wv * 16;
    int rp = row_ptr[nb + (lane & 31) % 17];   // lanes 0..16 hold row_ptr[nb..nb+16]
    rp = __shfl(rp, lane % 17);                // broadcast-safe: recompute below via shfl by index
    // (simpler + correct: just reload per node via shfl from a 17-lane stripe)
    int rp17 = (lane < 17) ? row_ptr[nb + lane] : 0;
    for (int t = 0; t < 16; ++t) {
        int beg = __shfl(rp17, t), end = __shfl(rp17, t + 1);
        float a[8] = {};
        int j = beg + lg;
        for (; j + 12 < end; j += 16) {
            int s0 = csr[j], s1 = csr[j + 4], s2 = csr[j + 8], s3 = csr[j + 12];
            uint4 v0 = *(const uint4*)(Hin + (size_t)s0 * 128 + lr * 8);
            uint4 v1 = *(const uint4*)(Hin + (size_t)s1 * 128 + lr * 8);
            uint4 v2 = *(const uint4*)(Hin + (size_t)s2 * 128 + lr * 8);
            uint4 v3 = *(const uint4*)(Hin + (size_t)s3 * 128 + lr * 8);
            acc8(a, v0); acc8(a, v1); acc8(a, v2); acc8(a, v3);
        }
        for (; j < end; j += 4) {
            uint4 v = *(const uint4*)(Hin + (size_t)csr[j] * 128 + lr * 8);
            acc8(a, v);
        }
#pragma unroll
        for (int k = 0; k < 8; ++k) {
            a[k] += __shfl_xor(a[k], 16);
            a[k] += __shfl_xor(a[k], 32);
        }
        if (lg == 0) {
            float inv = 1.0f / fmaxf((float)(end - beg), 1.0f);
            uint4 o;
            o.x = f2b(a[0] * inv) | ((unsigned)f2b(a[1] * inv) << 16);
            o.y = f2b(a[2] * inv) | ((unsigned)f2b(a[3] * inv) << 16);
            o.z = f2b(a[4] * inv) | ((unsigned)f2b(a[5] * inv) << 16);
            o.w = f2b(a[6] * inv) | ((unsigned)f2b(a[7] * inv) << 16);
            int row = wv * 16 + t;
            int chunk = lr ^ (row & 15);            // swizzle
            *(uint4*)&agg_lds[row * 128 + chunk * 8] = o;
        }
    }
    __syncthreads();

    // phase 2: 4 M-tiles of 16 rows; A = self(global) + neigh(LDS)
    for (int tt = 0; tt < 4; ++tt) {
        int mr = tt * 16 + lr;
        bf16x8 afr[8];
#pragma unroll
        for (int kt = 0; kt < 4; ++kt)
            afr[kt] = *(const bf16x8*)(Hin + (size_t)(m0 + mr) * 128 + kt * 32 + lg * 8);
#pragma unroll
        for (int kt = 0; kt < 4; ++kt) {
            int chunk = (kt * 4 + lg) ^ (mr & 15);  // matching swizzle
            afr[4 + kt] = *(const bf16x8*)&agg_lds[mr * 128 + chunk * 8];
        }
        f32x4 acc[2];
#pragma unroll
        for (int c = 0; c < 2; ++c) acc[c] = (f32x4){0.f, 0.f, 0.f, 0.f};
#pragma unroll
        for (int kt = 0; kt < 8; ++kt)
#pragma unroll
            for (int c = 0; c < 2; ++c)
                acc[c] = __builtin_amdgcn_mfma_f32_16x16x32_bf16(afr[kt], bfr[c][kt], acc[c], 0, 0, 0);
#pragma unroll
        for (int c = 0; c < 2; ++c) {
            int n = (wv * 2 + c) * 16 + lr;
#pragma unroll
            for (int r = 0; r < 4; ++r) {
                int m = m0 + tt * 16 + lg * 4 + r;
                float v = acc[c][r] + bs[c];
                if (RELU) v = fmaxf(v, 0.f);
                Hout[(size_t)m * 128 + n] = f2b(v);
            }
        }
    }
}

// ---------------- layer-2 dual GEMM: one read of h2 -> out(self+bias) and Hn = h2@Wn2 ----------------
// 192 threads / 3 waves; wave wv owns tiles {2wv, 2wv+1} of 6 (0-2: self->out fp32, 3-5: neigh->Hn bf16)

__global__ __launch_bounds__(192) void dual_gemm_kernel(
    const unsigned short* __restrict__ H2,
    const unsigned short* __restrict__ Wt2s, const unsigned short* __restrict__ Wt2n,
    const float* __restrict__ b2,
    float* __restrict__ out, unsigned short* __restrict__ Hn) {
    int wv = threadIdx.x >> 6, lane = threadIdx.x & 63;
    int lr = lane & 15, lg = lane >> 4;

    bf16x8 bfr[2][4];
    float bs[2];
#pragma unroll
    for (int c = 0; c < 2; ++c) {
        int t = wv * 2 + c;
        bool is_s = t < 3;
        int n = (is_s ? t : t - 3) * 16 + lr;
        const unsigned short* W = is_s ? Wt2s : Wt2n;
#pragma unroll
        for (int kt = 0; kt < 4; ++kt)
            bfr[c][kt] = *(const bf16x8*)(W + (size_t)n * 128 + kt * 32 + lg * 8);
        bs[c] = (is_s && n < 47) ? b2[n] : 0.f;
    }

    for (int tt = 0; tt < 4; ++tt) {
        int m0 = blockIdx.x * 64 + tt * 16;
        bf16x8 afr[4];
#pragma unroll
        for (int kt = 0; kt < 4; ++kt)
            afr[kt] = *(const bf16x8*)(H2 + (size_t)(m0 + lr) * 128 + kt * 32 + lg * 8);
        f32x4 acc[2];
#pragma unroll
        for (int c = 0; c < 2; ++c) acc[c] = (f32x4){0.f, 0.f, 0.f, 0.f};
#pragma unroll
        for (int kt = 0; kt < 4; ++kt)
#pragma unroll
            for (int c = 0; c < 2; ++c)
                acc[c] = __builtin_amdgcn_mfma_f32_16x16x32_bf16(afr[kt], bfr[c][kt], acc[c], 0, 0, 0);
#pragma unroll
        for (int c = 0; c < 2; ++c) {
            int t = wv * 2 + c;
            bool is_s = t < 3;
            int n = (is_s ? t : t - 3) * 16 + lr;
#pragma unroll
            for (int r = 0; r < 4; ++r) {
                int m = m0 + lg * 4 + r;
                float v = acc[c][r] + bs[c];
                if (is_s) {
                    if (n < 47) out[(size_t)m * 47 + n] = v;
                } else {
                    Hn[(size_t)m * 48 + n] = f2b(v);   // cols>=47 are 0 (zeroed weights)
                }
            }
        }
    }
}

// ---------------- layer-2 neighbor mean in 47-col space, += into out ----------------
// Hn stride 48; 12 of 16 lanes per edge-group carry cols.

__global__ void aggregate_out_kernel(const unsigned short* __restrict__ Hn,
                                     const int* __restrict__ csr,
                                     const int* __restrict__ row_ptr,
                                     float* __restrict__ out) {
    int node = (blockIdx.x * blockDim.x + threadIdx.x) >> 6;
    int lane = threadIdx.x & 63;
    if (node >= NN) return;
    int eg = lane >> 4, lc = lane & 15;
    int beg = row_ptr[node], end = row_ptr[node + 1];
    float a[4] = {};
    int j = beg + eg;
    for (; j + 12 < end; j += 16) {
        int s0 = csr[j], s1 = csr[j + 4], s2 = csr[j + 8], s3 = csr[j + 12];
        uint2 v0 = *(const uint2*)(Hn + (size_t)s0 * 48 + lc * 4);
        uint2 v1 = *(const uint2*)(Hn + (size_t)s1 * 48 + lc * 4);
        uint2 v2 = *(const uint2*)(Hn + (size_t)s2 * 48 + lc * 4);
        uint2 v3 = *(const uint2*)(Hn + (size_t)s3 * 48 + lc * 4);
        acc4(a, v0); acc4(a, v1); acc4(a, v2); acc4(a, v3);
    }
    for (; j < end; j += 4) {
        uint2 v = *(const uint2*)(Hn + (size_t)csr[j] * 48 + lc * 4);
        acc4(a, v);
    }
#pragma unroll
    for (int k = 0; k < 4; ++k) {
        a[k] += __shfl_xor(a[k], 16);
        a[k] += __shfl_xor(a[k], 32);
    }
    if (eg == 0 && lc < 12) {
        float inv = 1.0f / fmaxf((float)(end - beg), 1.0f);
        int c0 = lc * 4;
#pragma unroll
        for (int r = 0; r < 4; ++r)
            if (c0 + r < 47) out[(size_t)node * 47 + c0 + r] += a[r] * inv;
    }
}

// ---------------- launch ----------------

extern "C" void kernel_launch(void* const* d_in, const int* in_sizes, int n_in,
                              void* d_out, int out_size, void* d_ws, size_t ws_size,
                              hipStream_t stream) {
    const float* x   = (const float*)d_in[0];
    const int*   src = (const int*)d_in[1];
    const int*   dst = (const int*)d_in[2];
    const float* Ws0 = (const float*)d_in[3];
    const float* Wn0 = (const float*)d_in[4];
    const float* b0  = (const float*)d_in[5];
    const float* Ws1 = (const float*)d_in[6];
    const float* Wn1 = (const float*)d_in[7];
    const float* b1  = (const float*)d_in[8];
    const float* Ws2 = (const float*)d_in[9];
    const float* Wn2 = (const float*)d_in[10];
    const float* b2  = (const float*)d_in[11];
    float* out = (float*)d_out;

    int* wsI     = (int*)d_ws;
    int* deg     = wsI;                 // 40000
    int* cursor  = wsI + 40000;         // 40000
    int* row_ptr = wsI + 80000;         // 40001 (pad to 40004)
    int* csr     = wsI + 120004;        // 640000
    unsigned short* X   = (unsigned short*)(wsI + 760004);  // [40000][128]
    unsigned short* H1  = X + (size_t)NN * 128;             // [40000][128]
    unsigned short* H2  = X;                                // alias: X dead after layer 0
    unsigned short* Wt0 = H1 + (size_t)NN * 128;            // [128][256]
    unsigned short* Wt1 = Wt0 + 128 * 256;                  // [128][256]
    unsigned short* Wt2s = Wt1 + 128 * 256;                 // [48][128]
    unsigned short* Wt2n = Wt2s + 48 * 128;                 // [48][128]
    unsigned short* Hn  = Wt2n + 48 * 128;                  // [40000][48] + pad
    int* bsum = (int*)(Hn + (size_t)NN * 48 + 64);          // [NB]
    int* btop = bsum + NB;                                  // [NB]

    prep_kernel<<<5383, 256, 0, stream>>>(x, Ws0, Wn0, Ws1, Wn1, Ws2, Wn2,
                                          deg, X, Wt0, Wt1, Wt2s, Wt2n);
    count_deg_kernel<<<2500, 256, 0, stream>>>(dst, deg, NE);
    scan1_kernel<<<NB, 256, 0, stream>>>(deg, bsum);
    scan_top_kernel<<<1, 64, 0, stream>>>(bsum, btop);
    scan2_kernel<<<NB, 256, 0, stream>>>(deg, btop, row_ptr);
    fill_csr_kernel<<<2500, 256, 0, stream>>>(src, dst, row_ptr, cursor, csr, NE);

    sage_layer_kernel<true><<<625, 256, 0, stream>>>(X, csr, row_ptr, Wt0, b0, H1);
    sage_layer_kernel<true><<<625, 256, 0, stream>>>(H1, csr, row_ptr, Wt1, b1, H2);
    dual_gemm_kernel<<<625, 192, 0, stream>>>(H2, Wt2s, Wt2n, b2, out, Hn);
    aggregate_out_kernel<<<10000, 256, 0, stream>>>(Hn, csr, row_ptr, out);
}

// Round 6
// 214.314 us; speedup vs baseline: 2.6573x; 1.0099x over previous
//
#include <hip/hip_runtime.h>
#include <hip/hip_bf16.h>

#define NN 40000
#define NE 640000
#define NB 157   // ceil(NN/256)

typedef __attribute__((ext_vector_type(8))) short bf16x8;
typedef __attribute__((ext_vector_type(4))) float f32x4;

static __device__ __forceinline__ unsigned short f2b(float f) {
    unsigned b = __float_as_uint(f);
    return (unsigned short)((b + 0x7FFFu + ((b >> 16) & 1u)) >> 16);
}
static __device__ __forceinline__ float blo(unsigned v) { return __uint_as_float(v << 16); }
static __device__ __forceinline__ float bhi(unsigned v) { return __uint_as_float(v & 0xffff0000u); }

static __device__ __forceinline__ void acc8(float* a, uint4 v) {
    a[0] += blo(v.x); a[1] += bhi(v.x);
    a[2] += blo(v.y); a[3] += bhi(v.y);
    a[4] += blo(v.z); a[5] += bhi(v.z);
    a[6] += blo(v.w); a[7] += bhi(v.w);
}
static __device__ __forceinline__ void acc4(float* a, uint2 v) {
    a[0] += blo(v.x); a[1] += bhi(v.x);
    a[2] += blo(v.y); a[3] += bhi(v.y);
}

// ---------------- CSR build ----------------

__global__ void count_deg_kernel(const int* __restrict__ dst, int* __restrict__ deg, int n) {
    int i = blockIdx.x * blockDim.x + threadIdx.x;
    if (i < n) atomicAdd(&deg[dst[i]], 1);
}

__global__ __launch_bounds__(256) void scan1_kernel(const int* __restrict__ deg,
                                                    int* __restrict__ bsum) {
    int i = blockIdx.x * 256 + threadIdx.x;
    int v = (i < NN) ? deg[i] : 0;
#pragma unroll
    for (int off = 1; off < 64; off <<= 1) v += __shfl_xor(v, off);
    __shared__ int ws4[4];
    if ((threadIdx.x & 63) == 0) ws4[threadIdx.x >> 6] = v;
    __syncthreads();
    if (threadIdx.x == 0) bsum[blockIdx.x] = ws4[0] + ws4[1] + ws4[2] + ws4[3];
}

__global__ void scan_top_kernel(const int* __restrict__ bsum, int* __restrict__ btop) {
    int lane = threadIdx.x;
    int run = 0;
    for (int base = 0; base < NB; base += 64) {
        int idx = base + lane;
        int v = (idx < NB) ? bsum[idx] : 0;
        int s = v;
#pragma unroll
        for (int off = 1; off < 64; off <<= 1) { int t = __shfl_up(s, off); if (lane >= off) s += t; }
        if (idx < NB) btop[idx] = run + s - v;
        run += __shfl(s, 63);
    }
}

__global__ __launch_bounds__(256) void scan2_kernel(const int* __restrict__ deg,
                                                    const int* __restrict__ btop,
                                                    int* __restrict__ row_ptr) {
    int b = blockIdx.x;
    int i = b * 256 + threadIdx.x;
    int lane = threadIdx.x & 63, wv = threadIdx.x >> 6;
    int v = (i < NN) ? deg[i] : 0;
    int s = v;
#pragma unroll
    for (int off = 1; off < 64; off <<= 1) { int t = __shfl_up(s, off); if (lane >= off) s += t; }
    __shared__ int wsum[4];
    if (lane == 63) wsum[wv] = s;
    __syncthreads();
    int add = btop[b];
    for (int w = 0; w < wv; ++w) add += wsum[w];
    if (i < NN) row_ptr[i] = add + s - v;
    if (i == NN - 1) row_ptr[NN] = add + s;
}

__global__ void fill_csr_kernel(const int* __restrict__ src, const int* __restrict__ dst,
                                const int* __restrict__ row_ptr, int* __restrict__ cursor,
                                int* __restrict__ csr, int n) {
    int i = blockIdx.x * blockDim.x + threadIdx.x;
    if (i < n) {
        int d = dst[i];
        int pos = row_ptr[d] + atomicAdd(&cursor[d], 1);
        csr[pos] = src[i];
    }
}

// ---------------- fused prep: zero deg/cursor + cast x + build weights ----------------

__global__ __launch_bounds__(256) void prep_kernel(
    const float* __restrict__ x,
    const float* __restrict__ Ws0, const float* __restrict__ Wn0,
    const float* __restrict__ Ws1, const float* __restrict__ Wn1,
    const float* __restrict__ Ws2, const float* __restrict__ Wn2,
    int* __restrict__ zero_base, unsigned short* __restrict__ X,
    unsigned short* __restrict__ Wt0, unsigned short* __restrict__ Wt1,
    unsigned short* __restrict__ Wt2s, unsigned short* __restrict__ Wt2n) {
    int b = blockIdx.x, tid = threadIdx.x;
    if (b < 79) {
        int i = (b * 256 + tid) * 4;
        if (i < 80000) *(int4*)(zero_base + i) = (int4){0, 0, 0, 0};
    } else if (b < 5079) {
        int i = (b - 79) * 256 + tid;   // one per 4 elems of x
        int e = i << 2;
        float4 v = *(const float4*)(x + e);
        uint2 o;
        o.x = f2b(v.x) | ((unsigned)f2b(v.y) << 16);
        o.y = f2b(v.z) | ((unsigned)f2b(v.w) << 16);
        *(uint2*)(X + e) = o;   // X is [NN][128], same flat layout as x
    } else {
        int i = (b - 5079) * 256 + tid;
        if (i < 65536) {
            // Wt0/Wt1: [128 n][256 k], k<128 = Ws rows, k>=128 = Wn rows
            int l = i >> 15, j = i & 32767;
            int n = j >> 8, k = j & 255;
            const float* Ws = l ? Ws1 : Ws0;
            const float* Wn = l ? Wn1 : Wn0;
            float v = (k < 128) ? Ws[k * 128 + n] : Wn[(k - 128) * 128 + n];
            (l ? Wt1 : Wt0)[n * 256 + k] = f2b(v);
        } else if (i < 65536 + 6144) {
            int j = i - 65536;                  // Wt2s: [48 n][128 k]
            int n = j >> 7, k = j & 127;
            float v = (n < 47) ? Ws2[k * 47 + n] : 0.f;
            Wt2s[n * 128 + k] = f2b(v);
        } else if (i < 65536 + 12288) {
            int j = i - 65536 - 6144;           // Wt2n: [48 n][128 k]
            int n = j >> 7, k = j & 127;
            float v = (n < 47) ? Wn2[k * 47 + n] : 0.f;
            Wt2n[n * 128 + k] = f2b(v);
        }
    }
}

// ---------------- fused SAGE layer: 16 nodes/block, gather->LDS, then MFMA ----------------
// Hin/Hout: [NN][128] bf16. Wt: [128 n][256 k] (k<128 self, k>=128 neigh).
// 256 threads / 4 waves. Each wave gathers 4 nodes, then owns 2 col-tiles of one
// 16-row M-tile. B streamed from L2 (no per-block reuse to exploit).

template <bool RELU>
__global__ __launch_bounds__(256) void sage_layer_kernel(
    const unsigned short* __restrict__ Hin,
    const int* __restrict__ csr, const int* __restrict__ row_ptr,
    const unsigned short* __restrict__ Wt, const float* __restrict__ bias,
    unsigned short* __restrict__ Hout) {
    // [16 rows][16 chunks of 16B], chunk XOR-swizzled by row to kill bank conflicts
    __shared__ unsigned short agg_lds[16 * 128];

    int tid = threadIdx.x;
    int wv = tid >> 6, lane = tid & 63;
    int lr = lane & 15, lg = lane >> 4;
    int m0 = blockIdx.x * 16;

    // phase 1: gather-mean, 4 nodes per wave (4 edge-groups x 16 lanes, unroll 4)
    int nb = m0 + wv * 4;
    int rp5 = (lane < 5) ? row_ptr[nb + lane] : 0;
    for (int t = 0; t < 4; ++t) {
        int beg = __shfl(rp5, t), end = __shfl(rp5, t + 1);
        float a[8] = {};
        int j = beg + lg;
        for (; j + 12 < end; j += 16) {
            int s0 = csr[j], s1 = csr[j + 4], s2 = csr[j + 8], s3 = csr[j + 12];
            uint4 v0 = *(const uint4*)(Hin + (size_t)s0 * 128 + lr * 8);
            uint4 v1 = *(const uint4*)(Hin + (size_t)s1 * 128 + lr * 8);
            uint4 v2 = *(const uint4*)(Hin + (size_t)s2 * 128 + lr * 8);
            uint4 v3 = *(const uint4*)(Hin + (size_t)s3 * 128 + lr * 8);
            acc8(a, v0); acc8(a, v1); acc8(a, v2); acc8(a, v3);
        }
        for (; j < end; j += 4) {
            uint4 v = *(const uint4*)(Hin + (size_t)csr[j] * 128 + lr * 8);
            acc8(a, v);
        }
#pragma unroll
        for (int k = 0; k < 8; ++k) {
            a[k] += __shfl_xor(a[k], 16);
            a[k] += __shfl_xor(a[k], 32);
        }
        if (lg == 0) {
            float inv = 1.0f / fmaxf((float)(end - beg), 1.0f);
            uint4 o;
            o.x = f2b(a[0] * inv) | ((unsigned)f2b(a[1] * inv) << 16);
            o.y = f2b(a[2] * inv) | ((unsigned)f2b(a[3] * inv) << 16);
            o.z = f2b(a[4] * inv) | ((unsigned)f2b(a[5] * inv) << 16);
            o.w = f2b(a[6] * inv) | ((unsigned)f2b(a[7] * inv) << 16);
            int row = wv * 4 + t;
            int chunk = lr ^ row;                   // swizzle
            *(uint4*)&agg_lds[row * 128 + chunk * 8] = o;
        }
    }
    __syncthreads();

    // phase 2: one 16-row M-tile; A = self(global) + neigh(LDS); B streamed
    bf16x8 afr[8];
#pragma unroll
    for (int kt = 0; kt < 4; ++kt)
        afr[kt] = *(const bf16x8*)(Hin + (size_t)(m0 + lr) * 128 + kt * 32 + lg * 8);
#pragma unroll
    for (int kt = 0; kt < 4; ++kt) {
        int chunk = (kt * 4 + lg) ^ lr;             // matching swizzle (row = lr)
        afr[4 + kt] = *(const bf16x8*)&agg_lds[lr * 128 + chunk * 8];
    }

    int n0 = (wv * 2) * 16 + lr;
    int n1 = n0 + 16;
    f32x4 acc0 = (f32x4){0.f, 0.f, 0.f, 0.f};
    f32x4 acc1 = (f32x4){0.f, 0.f, 0.f, 0.f};
#pragma unroll
    for (int kt = 0; kt < 8; ++kt) {
        bf16x8 b0 = *(const bf16x8*)(Wt + (size_t)n0 * 256 + kt * 32 + lg * 8);
        bf16x8 b1 = *(const bf16x8*)(Wt + (size_t)n1 * 256 + kt * 32 + lg * 8);
        acc0 = __builtin_amdgcn_mfma_f32_16x16x32_bf16(afr[kt], b0, acc0, 0, 0, 0);
        acc1 = __builtin_amdgcn_mfma_f32_16x16x32_bf16(afr[kt], b1, acc1, 0, 0, 0);
    }

    float bs0 = bias[n0], bs1 = bias[n1];
#pragma unroll
    for (int r = 0; r < 4; ++r) {
        int m = m0 + lg * 4 + r;
        float v0 = acc0[r] + bs0;
        float v1 = acc1[r] + bs1;
        if (RELU) { v0 = fmaxf(v0, 0.f); v1 = fmaxf(v1, 0.f); }
        Hout[(size_t)m * 128 + n0] = f2b(v0);
        Hout[(size_t)m * 128 + n1] = f2b(v1);
    }
}

// ---------------- layer-2 dual GEMM: one read of h2 -> out(self+bias) and Hn = h2@Wn2 ----------------
// 192 threads / 3 waves; wave wv owns tiles {2wv, 2wv+1} of 6 (0-2: self->out fp32, 3-5: neigh->Hn bf16)

__global__ __launch_bounds__(192) void dual_gemm_kernel(
    const unsigned short* __restrict__ H2,
    const unsigned short* __restrict__ Wt2s, const unsigned short* __restrict__ Wt2n,
    const float* __restrict__ b2,
    float* __restrict__ out, unsigned short* __restrict__ Hn) {
    int wv = threadIdx.x >> 6, lane = threadIdx.x & 63;
    int lr = lane & 15, lg = lane >> 4;

    bf16x8 bfr[2][4];
    float bs[2];
#pragma unroll
    for (int c = 0; c < 2; ++c) {
        int t = wv * 2 + c;
        bool is_s = t < 3;
        int n = (is_s ? t : t - 3) * 16 + lr;
        const unsigned short* W = is_s ? Wt2s : Wt2n;
#pragma unroll
        for (int kt = 0; kt < 4; ++kt)
            bfr[c][kt] = *(const bf16x8*)(W + (size_t)n * 128 + kt * 32 + lg * 8);
        bs[c] = (is_s && n < 47) ? b2[n] : 0.f;
    }

    for (int tt = 0; tt < 2; ++tt) {
        int m0 = blockIdx.x * 32 + tt * 16;
        bf16x8 afr[4];
#pragma unroll
        for (int kt = 0; kt < 4; ++kt)
            afr[kt] = *(const bf16x8*)(H2 + (size_t)(m0 + lr) * 128 + kt * 32 + lg * 8);
        f32x4 acc[2];
#pragma unroll
        for (int c = 0; c < 2; ++c) acc[c] = (f32x4){0.f, 0.f, 0.f, 0.f};
#pragma unroll
        for (int kt = 0; kt < 4; ++kt)
#pragma unroll
            for (int c = 0; c < 2; ++c)
                acc[c] = __builtin_amdgcn_mfma_f32_16x16x32_bf16(afr[kt], bfr[c][kt], acc[c], 0, 0, 0);
#pragma unroll
        for (int c = 0; c < 2; ++c) {
            int t = wv * 2 + c;
            bool is_s = t < 3;
            int n = (is_s ? t : t - 3) * 16 + lr;
#pragma unroll
            for (int r = 0; r < 4; ++r) {
                int m = m0 + lg * 4 + r;
                float v = acc[c][r] + bs[c];
                if (is_s) {
                    if (n < 47) out[(size_t)m * 47 + n] = v;
                } else {
                    Hn[(size_t)m * 48 + n] = f2b(v);   // cols>=47 are 0 (zeroed weights)
                }
            }
        }
    }
}

// ---------------- layer-2 neighbor mean in 47-col space, += into out ----------------
// Hn stride 48; 12 of 16 lanes per edge-group carry cols.

__global__ void aggregate_out_kernel(const unsigned short* __restrict__ Hn,
                                     const int* __restrict__ csr,
                                     const int* __restrict__ row_ptr,
                                     float* __restrict__ out) {
    int node = (blockIdx.x * blockDim.x + threadIdx.x) >> 6;
    int lane = threadIdx.x & 63;
    if (node >= NN) return;
    int eg = lane >> 4, lc = lane & 15;
    int beg = row_ptr[node], end = row_ptr[node + 1];
    float a[4] = {};
    int j = beg + eg;
    for (; j + 12 < end; j += 16) {
        int s0 = csr[j], s1 = csr[j + 4], s2 = csr[j + 8], s3 = csr[j + 12];
        uint2 v0 = *(const uint2*)(Hn + (size_t)s0 * 48 + lc * 4);
        uint2 v1 = *(const uint2*)(Hn + (size_t)s1 * 48 + lc * 4);
        uint2 v2 = *(const uint2*)(Hn + (size_t)s2 * 48 + lc * 4);
        uint2 v3 = *(const uint2*)(Hn + (size_t)s3 * 48 + lc * 4);
        acc4(a, v0); acc4(a, v1); acc4(a, v2); acc4(a, v3);
    }
    for (; j < end; j += 4) {
        uint2 v = *(const uint2*)(Hn + (size_t)csr[j] * 48 + lc * 4);
        acc4(a, v);
    }
#pragma unroll
    for (int k = 0; k < 4; ++k) {
        a[k] += __shfl_xor(a[k], 16);
        a[k] += __shfl_xor(a[k], 32);
    }
    if (eg == 0 && lc < 12) {
        float inv = 1.0f / fmaxf((float)(end - beg), 1.0f);
        int c0 = lc * 4;
#pragma unroll
        for (int r = 0; r < 4; ++r)
            if (c0 + r < 47) out[(size_t)node * 47 + c0 + r] += a[r] * inv;
    }
}

// ---------------- launch ----------------

extern "C" void kernel_launch(void* const* d_in, const int* in_sizes, int n_in,
                              void* d_out, int out_size, void* d_ws, size_t ws_size,
                              hipStream_t stream) {
    const float* x   = (const float*)d_in[0];
    const int*   src = (const int*)d_in[1];
    const int*   dst = (const int*)d_in[2];
    const float* Ws0 = (const float*)d_in[3];
    const float* Wn0 = (const float*)d_in[4];
    const float* b0  = (const float*)d_in[5];
    const float* Ws1 = (const float*)d_in[6];
    const float* Wn1 = (const float*)d_in[7];
    const float* b1  = (const float*)d_in[8];
    const float* Ws2 = (const float*)d_in[9];
    const float* Wn2 = (const float*)d_in[10];
    const float* b2  = (const float*)d_in[11];
    float* out = (float*)d_out;

    int* wsI     = (int*)d_ws;
    int* deg     = wsI;                 // 40000
    int* cursor  = wsI + 40000;         // 40000
    int* row_ptr = wsI + 80000;         // 40001 (pad to 40004)
    int* csr     = wsI + 120004;        // 640000
    unsigned short* X   = (unsigned short*)(wsI + 760004);  // [40000][128]
    unsigned short* H1  = X + (size_t)NN * 128;             // [40000][128]
    unsigned short* H2  = X;                                // alias: X dead after layer 0
    unsigned short* Wt0 = H1 + (size_t)NN * 128;            // [128][256]
    unsigned short* Wt1 = Wt0 + 128 * 256;                  // [128][256]
    unsigned short* Wt2s = Wt1 + 128 * 256;                 // [48][128]
    unsigned short* Wt2n = Wt2s + 48 * 128;                 // [48][128]
    unsigned short* Hn  = Wt2n + 48 * 128;                  // [40000][48] + pad
    int* bsum = (int*)(Hn + (size_t)NN * 48 + 64);          // [NB]
    int* btop = bsum + NB;                                  // [NB]

    prep_kernel<<<5383, 256, 0, stream>>>(x, Ws0, Wn0, Ws1, Wn1, Ws2, Wn2,
                                          deg, X, Wt0, Wt1, Wt2s, Wt2n);
    count_deg_kernel<<<2500, 256, 0, stream>>>(dst, deg, NE);
    scan1_kernel<<<NB, 256, 0, stream>>>(deg, bsum);
    scan_top_kernel<<<1, 64, 0, stream>>>(bsum, btop);
    scan2_kernel<<<NB, 256, 0, stream>>>(deg, btop, row_ptr);
    fill_csr_kernel<<<2500, 256, 0, stream>>>(src, dst, row_ptr, cursor, csr, NE);

    sage_layer_kernel<true><<<2500, 256, 0, stream>>>(X, csr, row_ptr, Wt0, b0, H1);
    sage_layer_kernel<true><<<2500, 256, 0, stream>>>(H1, csr, row_ptr, Wt1, b1, H2);
    dual_gemm_kernel<<<1250, 192, 0, stream>>>(H2, Wt2s, Wt2n, b2, out, Hn);
    aggregate_out_kernel<<<10000, 256, 0, stream>>>(Hn, csr, row_ptr, out);
}